// Round 1
// 946.325 us; speedup vs baseline: 1.4343x; 1.4343x over previous
//
#include <hip/hip_runtime.h>
#include <hip/hip_bf16.h>
#include <cstdint>

#define B 128
#define T 400
#define H 512
#define H2 1024
#define H4 2048
#define E 128
#define V 50000
#define KPG 2176   // 4H+E
#define EPSF 1e-12f

// output element offsets (element counts identical for bf16/f32)
#define OFF_FIN 0
#define OFF_H   (B*V)
#define OFF_C   (OFF_H + B*H)
#define OFF_CT  (OFF_C + B*H)
#define OFF_AT  (OFF_CT + B*H2)
#define OFF_PG  (OFF_AT + B*T)
#define OFF_COV (OFF_PG + B)

// ---------------- IO policies: bf16 vs f32 ----------------
struct IOb {
  using OT = __hip_bfloat16;
  static __device__ __forceinline__ bool want(const float* fl){ return fl[0] > 0.5f; }
  static __device__ __forceinline__ float ld(const void* p, size_t i){
    return __uint_as_float(((unsigned)((const unsigned short*)p)[i]) << 16);
  }
  static __device__ __forceinline__ void ld8(const void* p, size_t i, float* f){
    uint4 u = *reinterpret_cast<const uint4*>((const unsigned short*)p + i);
    f[0]=__uint_as_float(u.x<<16); f[1]=__uint_as_float(u.x&0xffff0000u);
    f[2]=__uint_as_float(u.y<<16); f[3]=__uint_as_float(u.y&0xffff0000u);
    f[4]=__uint_as_float(u.z<<16); f[5]=__uint_as_float(u.z&0xffff0000u);
    f[6]=__uint_as_float(u.w<<16); f[7]=__uint_as_float(u.w&0xffff0000u);
  }
  static __device__ __forceinline__ void ld4(const void* p, size_t i, float* f){
    uint2 u = *reinterpret_cast<const uint2*>((const unsigned short*)p + i);
    f[0]=__uint_as_float(u.x<<16); f[1]=__uint_as_float(u.x&0xffff0000u);
    f[2]=__uint_as_float(u.y<<16); f[3]=__uint_as_float(u.y&0xffff0000u);
  }
  static __device__ __forceinline__ void st(void* p, size_t i, float v){
    ((__hip_bfloat16*)p)[i] = __float2bfloat16(v);
  }
  static __device__ __forceinline__ void st8(void* p, size_t i, const float* f){
    __hip_bfloat16 h[8];
    #pragma unroll
    for(int j=0;j<8;j++) h[j]=__float2bfloat16(f[j]);
    *reinterpret_cast<uint4*>((__hip_bfloat16*)p + i) = *reinterpret_cast<const uint4*>(h);
  }
};
struct IOf {
  using OT = float;
  static __device__ __forceinline__ bool want(const float* fl){ return fl[0] < 0.5f; }
  static __device__ __forceinline__ float ld(const void* p, size_t i){
    return ((const float*)p)[i];
  }
  static __device__ __forceinline__ void ld8(const void* p, size_t i, float* f){
    const float* q = (const float*)p + i;
    float4 a = *reinterpret_cast<const float4*>(q);
    float4 b = *reinterpret_cast<const float4*>(q+4);
    f[0]=a.x; f[1]=a.y; f[2]=a.z; f[3]=a.w;
    f[4]=b.x; f[5]=b.y; f[6]=b.z; f[7]=b.w;
  }
  static __device__ __forceinline__ void ld4(const void* p, size_t i, float* f){
    float4 a = *reinterpret_cast<const float4*>((const float*)p + i);
    f[0]=a.x; f[1]=a.y; f[2]=a.z; f[3]=a.w;
  }
  static __device__ __forceinline__ void st(void* p, size_t i, float v){
    ((float*)p)[i] = v;
  }
  static __device__ __forceinline__ void st8(void* p, size_t i, const float* f){
    float* q = (float*)p + i;
    *reinterpret_cast<float4*>(q)   = make_float4(f[0],f[1],f[2],f[3]);
    *reinterpret_cast<float4*>(q+4) = make_float4(f[4],f[5],f[6],f[7]);
  }
};

__device__ __forceinline__ float ftanh(float x){
  x = fminf(10.f, fmaxf(-10.f, x));
  float a = __expf(2.f*x);
  return 1.f - 2.f/(a+1.f);
}
__device__ __forceinline__ float fsig(float x){ return 1.f/(1.f+__expf(-x)); }

__device__ __forceinline__ float waveSum(float v){
  #pragma unroll
  for(int o=32;o>0;o>>=1) v += __shfl_down(v,o);
  return v;
}
__device__ __forceinline__ float waveMax(float v){
  #pragma unroll
  for(int o=32;o>0;o>>=1) v = fmaxf(v,__shfl_down(v,o));
  return v;
}

__device__ __forceinline__ void ldf8(const float* p, float* f){
  float4 a = *reinterpret_cast<const float4*>(p);
  float4 b = *reinterpret_cast<const float4*>(p+4);
  f[0]=a.x; f[1]=a.y; f[2]=a.z; f[3]=a.w;
  f[4]=b.x; f[5]=b.y; f[6]=b.z; f[7]=b.w;
}
__device__ __forceinline__ void stf8(float* p, const float* f){
  *reinterpret_cast<float4*>(p)   = make_float4(f[0],f[1],f[2],f[3]);
  *reinterpret_cast<float4*>(p+4) = make_float4(f[4],f[5],f[6],f[7]);
}

// detect input dtype from mask_select (all ones): bf16 pair 1.0,1.0 = 0x3F803F80
__global__ void k_detect(const void* mask, float* flagp){
  if(blockIdx.x==0 && threadIdx.x==0){
    unsigned u = *(const unsigned*)mask;
    flagp[0] = (((u>>16)==0x3F80u) && ((u&0xFFFFu)==0x3F80u)) ? 1.f : 0.f;
  }
}

__global__ void k_zero4(float4* p, int n){
  int i = blockIdx.x*256+threadIdx.x; if(i<n) p[i]=make_float4(0.f,0.f,0.f,0.f);
}

// P0: build A0 = [c_t_1 | emb[y]] as f32  (grid B, block 192, tid<144 active)
template<class IO>
__global__ void k_prep0(const float* flag, const int* y, const void* c_t_1, const void* emb, float* A0){
  if(!IO::want(flag)) return;
  int b = blockIdx.x, tid = threadIdx.x;
  float f[8];
  if(tid < 128){
    IO::ld8(c_t_1, (size_t)b*H2 + tid*8, f);
    stf8(A0 + (size_t)b*1152 + tid*8, f);
  } else if(tid < 144){
    int yb = y[b];
    IO::ld8(emb, (size_t)yb*E + (tid-128)*8, f);
    stf8(A0 + (size_t)b*1152 + H2 + (tid-128)*8, f);
  }
}

// P1: A1 h-columns = f32(h0)  (grid 32, block 256, 8 elems/thread over B*H)
template<class IO>
__global__ void k_prep_h(const float* flag, const void* h0, float* A1){
  if(!IO::want(flag)) return;
  int t = blockIdx.x*256 + threadIdx.x;
  int n = (t*8)&511, b = (t*8)>>9;
  float f[8];
  IO::ld8(h0, (size_t)b*H + n, f);
  stf8(A1 + (size_t)b*640 + E + n, f);
}

// G: generic split-K small GEMM.  C[b][j] (+)= sum_k A[b][k]*W[j][k] (+bias on kz==0)
// tile: 32 j x 64 b, K-chunks of 32 staged in LDS; grid (N/32, 128/64, KS); CH chunks/block.
// W given as up to 2 row-contiguous segments [W0 (K0 cols) | W1 (K1 cols)]; chunks never straddle.
template<class IO>
__global__ __launch_bounds__(256) void k_gemm(const float* flag, const float* A, int lda,
    const void* W0, int K0, const void* W1, int K1,
    const void* bias, float* C, int ldc, int CH){
  if(!IO::want(flag)) return;
  __shared__ float as[32][66];   // [k][b], pad 66: float2 aligned, 2-way banks (free)
  __shared__ float wsm[32][36];  // [k][j], pad 36: float4 aligned, broadcast reads
  int tid = threadIdx.x;
  int j0 = blockIdx.x*32;
  int b0 = blockIdx.y*64;
  int kz = blockIdx.z;
  int bq = tid & 31, jg = tid >> 5;
  float acc[2][4];
  #pragma unroll
  for(int i=0;i<2;i++){
    #pragma unroll
    for(int jj=0;jj<4;jj++) acc[i][jj]=0.f;
  }
  int arow = tid>>2, ac = (tid&3)*8;   // A stage: 64 rows x 32 k, 4 thr/row (128B chunks)

  for(int ci=0; ci<CH; ci++){
    int k0 = (kz*CH + ci)*32;
    __syncthreads();
    { // stage A (f32, coalesced 128B per 4 threads)
      const float* p = A + (size_t)(b0 + arow)*lda + k0 + ac;
      float4 q0 = *reinterpret_cast<const float4*>(p);
      float4 q1 = *reinterpret_cast<const float4*>(p+4);
      as[ac+0][arow]=q0.x; as[ac+1][arow]=q0.y; as[ac+2][arow]=q0.z; as[ac+3][arow]=q0.w;
      as[ac+4][arow]=q1.x; as[ac+5][arow]=q1.y; as[ac+6][arow]=q1.z; as[ac+7][arow]=q1.w;
    }
    if(tid < 128){ // stage W: 32 rows x 32 k, 4 thr/row
      const void* Wp; int st, kr;
      if(k0 < K0){ Wp=W0; st=K0; kr=k0; } else { Wp=W1; st=K1; kr=k0-K0; }
      int wrow = tid>>2, wc = (tid&3)*8;
      float f[8]; IO::ld8(Wp, (size_t)(j0+wrow)*st + kr + wc, f);
      #pragma unroll
      for(int i=0;i<8;i++) wsm[wc+i][wrow] = f[i];
    }
    __syncthreads();
    #pragma unroll
    for(int kk=0; kk<32; kk++){
      float2 a = *reinterpret_cast<const float2*>(&as[kk][bq*2]);
      float4 w = *reinterpret_cast<const float4*>(&wsm[kk][jg*4]);
      acc[0][0] += a.x*w.x; acc[0][1] += a.x*w.y; acc[0][2] += a.x*w.z; acc[0][3] += a.x*w.w;
      acc[1][0] += a.y*w.x; acc[1][1] += a.y*w.y; acc[1][2] += a.y*w.z; acc[1][3] += a.y*w.w;
    }
  }
  if(kz==0 && bias){
    #pragma unroll
    for(int jj=0;jj<4;jj++){
      float bv = IO::ld(bias, j0 + jg*4 + jj);
      acc[0][jj] += bv; acc[1][jj] += bv;
    }
  }
  #pragma unroll
  for(int i=0;i<2;i++){
    float* cp = C + (size_t)(b0 + bq*2 + i)*ldc + j0 + jg*4;
    atomicAdd(cp+0, acc[i][0]); atomicAdd(cp+1, acc[i][1]);
    atomicAdd(cp+2, acc[i][2]); atomicAdd(cp+3, acc[i][3]);
  }
}

// CELL: LSTM elementwise (grid 32, block 256, 8 elems/thread over B*H)
template<class IO>
__global__ void k_cell(const float* flag, const float* gts, const void* c0,
                       const void* b_ih, const void* b_hh,
                       float* A2, float* A3, void* dout){
  if(!IO::want(flag)) return;
  int t = blockIdx.x*256 + threadIdx.x;
  int n = (t*8)&511, b = (t*8)>>9;
  size_t gb = (size_t)b*H4 + n;
  float gi[8],gf[8],gg[8],go[8],c0v[8];
  ldf8(gts+gb,        gi); ldf8(gts+gb+H,   gf);
  ldf8(gts+gb+2*H,    gg); ldf8(gts+gb+3*H, go);
  float bi0[8],bi1[8],bi2[8],bi3[8],bh0[8],bh1[8],bh2[8],bh3[8];
  IO::ld8(b_ih, n, bi0); IO::ld8(b_ih, H+n, bi1); IO::ld8(b_ih, 2*H+n, bi2); IO::ld8(b_ih, 3*H+n, bi3);
  IO::ld8(b_hh, n, bh0); IO::ld8(b_hh, H+n, bh1); IO::ld8(b_hh, 2*H+n, bh2); IO::ld8(b_hh, 3*H+n, bh3);
  IO::ld8(c0, (size_t)b*H + n, c0v);
  float hv[8], cv[8];
  #pragma unroll
  for(int j=0;j<8;j++){
    float ig = fsig (gi[j]+bi0[j]+bh0[j]);
    float fg = fsig (gf[j]+bi1[j]+bh1[j]);
    float gv = ftanh(gg[j]+bi2[j]+bh2[j]);
    float og = fsig (go[j]+bi3[j]+bh3[j]);
    float c = fg*c0v[j] + ig*gv;
    cv[j]=c; hv[j]=og*ftanh(c);
  }
  stf8(A2 + (size_t)b*H2 + n,     hv);
  stf8(A2 + (size_t)b*H2 + H + n, cv);
  stf8(A3 + (size_t)b*1536 + n,   hv);
  IO::st8(dout, (size_t)OFF_H + (size_t)b*H + n, hv);
  IO::st8(dout, (size_t)OFF_C + (size_t)b*H + n, cv);
}

// K4: attention scores  (grid B*25, block 256 = 4 waves, 16 t per block)
template<class IO>
__global__ void k_scores(const float* flag, const void* enc_feat, const float* ws_dec,
                         const void* W_c, const void* v_w, const void* coverage,
                         float* ws_scores){
  if(!IO::want(flag)) return;
  int blk = blockIdx.x;
  int b  = blk / (T/16);
  int tb = (blk % (T/16))*16;
  int tid = threadIdx.x;
  int wave = tid >> 6, lane = tid & 63;
  int n0 = lane*16;
  float dec[16], wc[16], vw[16];
  #pragma unroll
  for(int i=0;i<16;i+=4){
    float4 v4 = *reinterpret_cast<const float4*>(ws_dec + b*H2 + n0 + i);
    dec[i]=v4.x; dec[i+1]=v4.y; dec[i+2]=v4.z; dec[i+3]=v4.w;
  }
  IO::ld8(W_c, n0, wc); IO::ld8(W_c, n0+8, wc+8);
  IO::ld8(v_w, n0, vw); IO::ld8(v_w, n0+8, vw+8);
  #pragma unroll
  for(int it=0; it<4; ++it){
    int t = tb + wave*4 + it;
    float cov = IO::ld(coverage, (size_t)b*T + t);
    size_t base = ((size_t)b*T + t)*H2 + n0;
    float ef[16]; IO::ld8(enc_feat, base, ef); IO::ld8(enc_feat, base+8, ef+8);
    float sum=0.f;
    #pragma unroll
    for(int i=0;i<16;i++){
      float s = ef[i] + dec[i] + cov*wc[i];
      sum += ftanh(s)*vw[i];
    }
    sum = waveSum(sum);
    if(lane==0) ws_scores[b*T + t] = sum;
  }
}

// K5: softmax over T + mask + renorm + coverage_next  (grid B, block 512)
template<class IO>
__global__ void k_attn(const float* flag, const float* ws_scores, const void* mask,
                       const void* coverage, float* ws_attn, void* dout){
  if(!IO::want(flag)) return;
  __shared__ float red[8];
  __shared__ float bc0, bc1, bc2;
  int b=blockIdx.x, tid=threadIdx.x;
  int lane = tid & 63, w = tid >> 6;
  float s = (tid<T)? ws_scores[b*T+tid] : -3.0e38f;
  float m = waveMax(s);
  if(lane==0) red[w]=m;
  __syncthreads();
  if(tid==0){ float v=red[0]; for(int i=1;i<8;i++)v=fmaxf(v,red[i]); bc0=v; }
  __syncthreads();
  float e = (tid<T)? __expf(s-bc0) : 0.f;
  float sm = waveSum(e);
  if(lane==0) red[w]=sm;
  __syncthreads();
  if(tid==0){ float v=0; for(int i=0;i<8;i++)v+=red[i]; bc1=v; }
  __syncthreads();
  float attn_ = (tid<T)? (e/bc1)*IO::ld(mask, (size_t)b*T+tid) : 0.f;
  float s2 = waveSum(attn_);
  if(lane==0) red[w]=s2;
  __syncthreads();
  if(tid==0){ float v=0; for(int i=0;i<8;i++)v+=red[i]; bc2=v; }
  __syncthreads();
  float attn = attn_/(bc2+EPSF);
  if(tid<T){
    ws_attn[b*T+tid]=attn;
    IO::st(dout, (size_t)OFF_AT + b*T+tid, attn);
    IO::st(dout, (size_t)OFF_COV + b*T+tid, IO::ld(coverage,(size_t)b*T+tid)+attn);
  }
}

// K6: c_t = attn @ encoder_outputs into A3 ct-columns  (grid B*8, block 256)
template<class IO>
__global__ void k_ctx(const float* flag, const void* enc_out, const float* ws_attn, float* A3){
  if(!IO::want(flag)) return;
  __shared__ float at[50];
  int b = blockIdx.x>>3, ch = blockIdx.x&7, tid=threadIdx.x;
  if(tid<50) at[tid] = ws_attn[b*T + ch*50 + tid];
  __syncthreads();
  int n0 = tid*4;
  float a0=0,a1=0,a2=0,a3=0;
  size_t base = ((size_t)b*T + ch*50)*H2 + n0;
  for(int t=0;t<50;t++){
    float a = at[t];
    float f[4]; IO::ld4(enc_out, base, f);
    a0 += a*f[0]; a1 += a*f[1]; a2 += a*f[2]; a3 += a*f[3];
    base += H2;
  }
  float* cp = A3 + (size_t)b*1536 + H + n0;
  atomicAdd(cp+0, a0); atomicAdd(cp+1, a1);
  atomicAdd(cp+2, a2); atomicAdd(cp+3, a3);
}

// K7: p_gen + write c_t out  (grid B, block 256)
template<class IO>
__global__ void k_pgen(const float* flag, const float* A1, const float* A2, const float* A3,
                       const void* W_pg, const void* b_pg, float* ws_pg, void* dout){
  if(!IO::want(flag)) return;
  __shared__ float red[4];
  int b=blockIdx.x, tid=threadIdx.x;
  int lane = tid&63, w = tid>>6;
  float part=0.f;
  for(int k=tid;k<KPG;k+=256){
    float xv;
    if(k<H2)            xv = A3[(size_t)b*1536 + H + k];          // c_t
    else if(k<H2+H)     xv = A2[(size_t)b*H2 + (k-H2)];           // h
    else if(k<2*H2)     xv = A2[(size_t)b*H2 + H + (k-H2-H)];     // c
    else                xv = A1[(size_t)b*640 + (k-2*H2)];        // x
    part += xv * IO::ld(W_pg, k);
  }
  part = waveSum(part);
  if(lane==0) red[w]=part;
  __syncthreads();
  if(tid==0){
    float v = red[0]+red[1]+red[2]+red[3] + IO::ld(b_pg, 0);
    float pg = fsig(v);
    ws_pg[b]=pg;
    IO::st(dout, (size_t)OFF_PG + b, pg);
  }
  for(int k=tid;k<H2;k+=256) IO::st(dout, (size_t)OFF_CT + b*H2+k, A3[(size_t)b*1536 + H + k]);
}

// K9: logits = o1 @ W_o2^T + b_o2   (grid ceil(V/64), block 256; tile 128b x 64v, K-chunk 32)
template<class IO>
__global__ __launch_bounds__(256) void k_logits(const float* flag, const float* ws_o1,
                                                const void* W_o2, const void* b_o2,
                                                float* ws_logits){
  if(!IO::want(flag)) return;
  __shared__ float o1s[32][132];
  __shared__ float wvs[32][68];
  int v0 = blockIdx.x * 64;
  int tid = threadIdx.x;
  int bg = tid & 31;   // b = bg*4 + i
  int vg = tid >> 5;   // v = v0 + vg*8 + j
  float acc[4][8];
  #pragma unroll
  for(int i=0;i<4;i++){
    #pragma unroll
    for(int j=0;j<8;j++) acc[i][j]=0.f; }
  for(int k0=0;k0<H;k0+=32){
    __syncthreads();
    { // stage o1: 128 rows x 32 k, 16 floats per thread
      int bb = tid>>1, kc = (tid&1)*16;
      const float* q = ws_o1 + bb*H + k0 + kc;
      float4 q0 = *reinterpret_cast<const float4*>(q);
      float4 q1 = *reinterpret_cast<const float4*>(q+4);
      float4 q2 = *reinterpret_cast<const float4*>(q+8);
      float4 q3 = *reinterpret_cast<const float4*>(q+12);
      o1s[kc+ 0][bb]=q0.x; o1s[kc+ 1][bb]=q0.y; o1s[kc+ 2][bb]=q0.z; o1s[kc+ 3][bb]=q0.w;
      o1s[kc+ 4][bb]=q1.x; o1s[kc+ 5][bb]=q1.y; o1s[kc+ 6][bb]=q1.z; o1s[kc+ 7][bb]=q1.w;
      o1s[kc+ 8][bb]=q2.x; o1s[kc+ 9][bb]=q2.y; o1s[kc+10][bb]=q2.z; o1s[kc+11][bb]=q2.w;
      o1s[kc+12][bb]=q3.x; o1s[kc+13][bb]=q3.y; o1s[kc+14][bb]=q3.z; o1s[kc+15][bb]=q3.w;
    }
    { // stage W_o2: 64 v x 32 k, 8 per thread
      int vv = tid>>2, c = (tid&3)*8;
      int v = v0+vv; bool ok = (v<V);
      float f[8]; IO::ld8(W_o2, (size_t)(ok? v : (V-1))*H + k0 + c, f);
      #pragma unroll
      for(int j=0;j<8;j++) wvs[c+j][vv] = ok? f[j] : 0.f;
    }
    __syncthreads();
    #pragma unroll 8
    for(int kk=0;kk<32;kk++){
      float4 a  = *reinterpret_cast<const float4*>(&o1s[kk][bg*4]);
      float4 w0 = *reinterpret_cast<const float4*>(&wvs[kk][vg*8]);
      float4 w1 = *reinterpret_cast<const float4*>(&wvs[kk][vg*8+4]);
      float av[4]={a.x,a.y,a.z,a.w};
      float wv[8]={w0.x,w0.y,w0.z,w0.w,w1.x,w1.y,w1.z,w1.w};
      #pragma unroll
      for(int i=0;i<4;i++){
        #pragma unroll
        for(int j=0;j<8;j++) acc[i][j] += av[i]*wv[j];
      }
    }
  }
  #pragma unroll
  for(int i=0;i<4;i++){
    int bb = bg*4+i;
    #pragma unroll
    for(int j=0;j<8;j++){
      int v = v0 + vg*8 + j;
      if(v<V) ws_logits[(size_t)bb*V + v] = acc[i][j] + IO::ld(b_o2, v);
    }
  }
}

// K10a: vocab softmax * p_gen, simple 3-pass  (grid B, block 256)
__global__ void k_vsoft(const float* lg, const float* pg, float* fin){
  __shared__ float red[4];
  __shared__ float bcast;
  int b=blockIdx.x, tid=threadIdx.x;
  int lane = tid&63, w = tid>>6;
  float m=-3.0e38f;
  for(int v=tid; v<V; v+=256) m = fmaxf(m, lg[(size_t)b*V+v]);
  m = waveMax(m);
  if(lane==0) red[w]=m;
  __syncthreads();
  if(tid==0) bcast = fmaxf(fmaxf(red[0],red[1]),fmaxf(red[2],red[3]));
  __syncthreads();
  float mx = bcast;
  float s=0.f;
  for(int v=tid; v<V; v+=256) s += __expf(lg[(size_t)b*V+v]-mx);
  s = waveSum(s);
  if(lane==0) red[w]=s;
  __syncthreads();
  if(tid==0) bcast = red[0]+red[1]+red[2]+red[3];
  __syncthreads();
  float scale = pg[b] / bcast;
  for(int v=tid; v<V; v+=256) fin[(size_t)b*V+v] = __expf(lg[(size_t)b*V+v]-mx)*scale;
}

// K10b: scatter-add (1-p_gen)*attn  (grid ceil(B*T/256))
__global__ void k_scatter(const int* ext, const float* ws_attn, const float* ws_pg, float* ws_final){
  int i = blockIdx.x*256+threadIdx.x;
  if(i>=B*T) return;
  int b=i/T;
  float add = (1.f-ws_pg[b])*ws_attn[i];
  atomicAdd(&ws_final[(size_t)b*V + ext[i]], add);
}

// K10c: store final dist to out, 8/thread
template<class IO>
__global__ void k_tostore(const float* flag, const float* src, void* dout, int n8){
  if(!IO::want(flag)) return;
  int i = blockIdx.x*256+threadIdx.x;
  if(i>=n8) return;
  size_t off = (size_t)i*8;
  float f[8];
  ldf8(src + off, f);
  IO::st8(dout, (size_t)OFF_FIN + off, f);
}

extern "C" void kernel_launch(void* const* d_in, const int* in_sizes, int n_in,
                              void* d_out, int out_size, void* d_ws, size_t ws_size,
                              hipStream_t stream){
  const int* y_t_1 = (const int*)d_in[0];
  const void* h0   =d_in[1];  const void* c0   =d_in[2];  const void* c_t_1=d_in[3];
  const void* enc_out=d_in[4]; const void* enc_feat=d_in[5]; const void* mask=d_in[6];
  const int* ext = (const int*)d_in[7];
  const void* coverage=d_in[8]; const void* emb=d_in[9];  const void* W_c=d_in[10];
  const void* W_dp=d_in[11];   const void* b_dp=d_in[12]; const void* v_w=d_in[13];
  const void* W_xc=d_in[14];   const void* b_xc=d_in[15];
  const void* W_ih=d_in[16];   const void* W_hh=d_in[17];
  const void* b_ih=d_in[18];   const void* b_hh=d_in[19];
  const void* W_pg=d_in[20];   const void* b_pg=d_in[21];
  const void* W_o1=d_in[22];   const void* b_o1=d_in[23];
  const void* W_o2=d_in[24];   const void* b_o2=d_in[25];

  float* ws = (float*)d_ws;
  // zero-initialized accumulation block (475136 f32 = 118784 float4):
  float* ws_A1  = ws;                        // [x(128) | h0(512)]  128*640
  float* ws_dec = ws_A1  + 128*640;          // 128*1024
  float* ws_o1  = ws_dec + 128*1024;         // 128*512
  float* ws_A3  = ws_o1  + 128*512;          // [h(512) | c_t(1024)] 128*1536
  // non-zeroed:
  float* ws_A2  = ws_A3  + 128*1536;         // [h(512) | c(512)]   128*1024
  float* ws_sc  = ws_A2  + 128*1024;         // B*T
  float* ws_attn= ws_sc  + B*T;              // B*T
  float* ws_pg  = ws_attn+ B*T;              // B
  float* ws_log = ws_pg  + B;                // B*V
  float* ws_gates = ws_log;                  // alias: 128*2048 (consumed before k_logits)
  float* ws_A0    = ws_log + 128*2048;       // alias: [c_t_1|emb] 128*1152
  float* ws_flag  = ws_log + (size_t)B*V;    // 4

  k_detect<<<dim3(1), dim3(64), 0, stream>>>(mask, ws_flag);
  k_zero4 <<<dim3(464), dim3(256), 0, stream>>>((float4*)ws, 118784);
  k_zero4 <<<dim3(256), dim3(256), 0, stream>>>((float4*)ws_gates, 65536);

  k_prep0<IOb><<<dim3(B), dim3(192), 0, stream>>>(ws_flag, y_t_1, c_t_1, emb, ws_A0);
  k_prep0<IOf><<<dim3(B), dim3(192), 0, stream>>>(ws_flag, y_t_1, c_t_1, emb, ws_A0);
  k_prep_h<IOb><<<dim3(32), dim3(256), 0, stream>>>(ws_flag, h0, ws_A1);
  k_prep_h<IOf><<<dim3(32), dim3(256), 0, stream>>>(ws_flag, h0, ws_A1);

  // embed: x = A0 @ W_xc^T + b_xc -> A1 x-columns.  N=128,K=1152, KS=12, CH=3
  k_gemm<IOb><<<dim3(4,2,12), dim3(256), 0, stream>>>(ws_flag, ws_A0, 1152, W_xc, 1152, nullptr, 0, b_xc, ws_A1, 640, 3);
  k_gemm<IOf><<<dim3(4,2,12), dim3(256), 0, stream>>>(ws_flag, ws_A0, 1152, W_xc, 1152, nullptr, 0, b_xc, ws_A1, 640, 3);

  // gates: A1 @ [W_ih|W_hh]^T -> ws_gates.  N=2048,K=640, KS=2, CH=10 (biases in k_cell)
  k_gemm<IOb><<<dim3(64,2,2), dim3(256), 0, stream>>>(ws_flag, ws_A1, 640, W_ih, E, W_hh, H, nullptr, ws_gates, H4, 10);
  k_gemm<IOf><<<dim3(64,2,2), dim3(256), 0, stream>>>(ws_flag, ws_A1, 640, W_ih, E, W_hh, H, nullptr, ws_gates, H4, 10);

  k_cell<IOb><<<dim3(32), dim3(256), 0, stream>>>(ws_flag, ws_gates, c0, b_ih, b_hh, ws_A2, ws_A3, d_out);
  k_cell<IOf><<<dim3(32), dim3(256), 0, stream>>>(ws_flag, ws_gates, c0, b_ih, b_hh, ws_A2, ws_A3, d_out);

  // dec_fea: A2 @ W_dp^T + b_dp -> ws_dec.  N=1024,K=1024, KS=4, CH=8
  k_gemm<IOb><<<dim3(32,2,4), dim3(256), 0, stream>>>(ws_flag, ws_A2, H2, W_dp, H2, nullptr, 0, b_dp, ws_dec, H2, 8);
  k_gemm<IOf><<<dim3(32,2,4), dim3(256), 0, stream>>>(ws_flag, ws_A2, H2, W_dp, H2, nullptr, 0, b_dp, ws_dec, H2, 8);

  k_scores<IOb><<<dim3(B*(T/16)), dim3(256), 0, stream>>>(ws_flag, enc_feat, ws_dec, W_c, v_w, coverage, ws_sc);
  k_scores<IOf><<<dim3(B*(T/16)), dim3(256), 0, stream>>>(ws_flag, enc_feat, ws_dec, W_c, v_w, coverage, ws_sc);

  k_attn<IOb><<<dim3(B), dim3(512), 0, stream>>>(ws_flag, ws_sc, mask, coverage, ws_attn, d_out);
  k_attn<IOf><<<dim3(B), dim3(512), 0, stream>>>(ws_flag, ws_sc, mask, coverage, ws_attn, d_out);

  k_ctx<IOb><<<dim3(B*8), dim3(256), 0, stream>>>(ws_flag, enc_out, ws_attn, ws_A3);
  k_ctx<IOf><<<dim3(B*8), dim3(256), 0, stream>>>(ws_flag, enc_out, ws_attn, ws_A3);

  k_pgen<IOb><<<dim3(B), dim3(256), 0, stream>>>(ws_flag, ws_A1, ws_A2, ws_A3, W_pg, b_pg, ws_pg, d_out);
  k_pgen<IOf><<<dim3(B), dim3(256), 0, stream>>>(ws_flag, ws_A1, ws_A2, ws_A3, W_pg, b_pg, ws_pg, d_out);

  // o1: A3 @ W_o1^T + b_o1 -> ws_o1.  N=512,K=1536, KS=8, CH=6
  k_gemm<IOb><<<dim3(16,2,8), dim3(256), 0, stream>>>(ws_flag, ws_A3, 1536, W_o1, 1536, nullptr, 0, b_o1, ws_o1, H, 6);
  k_gemm<IOf><<<dim3(16,2,8), dim3(256), 0, stream>>>(ws_flag, ws_A3, 1536, W_o1, 1536, nullptr, 0, b_o1, ws_o1, H, 6);

  k_logits<IOb><<<dim3((V+63)/64), dim3(256), 0, stream>>>(ws_flag, ws_o1, W_o2, b_o2, ws_log);
  k_logits<IOf><<<dim3((V+63)/64), dim3(256), 0, stream>>>(ws_flag, ws_o1, W_o2, b_o2, ws_log);

  k_vsoft   <<<dim3(B), dim3(256), 0, stream>>>(ws_log, ws_pg, ws_log);
  k_scatter <<<dim3((B*T+255)/256), dim3(256), 0, stream>>>(ext, ws_attn, ws_pg, ws_log);

  k_tostore<IOb><<<dim3((B*V/8+255)/256), dim3(256), 0, stream>>>(ws_flag, ws_log, d_out, B*V/8);
  k_tostore<IOf><<<dim3((B*V/8+255)/256), dim3(256), 0, stream>>>(ws_flag, ws_log, d_out, B*V/8);
}

// Round 2
// 825.497 us; speedup vs baseline: 1.6442x; 1.1464x over previous
//
#include <hip/hip_runtime.h>
#include <hip/hip_bf16.h>
#include <cstdint>

#define B 128
#define T 400
#define H 512
#define H2 1024
#define H4 2048
#define E 128
#define V 50000
#define KPG 2176   // 4H+E
#define EPSF 1e-12f
#define VCH 25
#define VCHUNK 2000

// output element offsets (element counts identical for bf16/f32)
#define OFF_FIN 0
#define OFF_H   (B*V)
#define OFF_C   (OFF_H + B*H)
#define OFF_CT  (OFF_C + B*H)
#define OFF_AT  (OFF_CT + B*H2)
#define OFF_PG  (OFF_AT + B*T)
#define OFF_COV (OFF_PG + B)

// ---------------- IO policies: bf16 vs f32 ----------------
struct IOb {
  using OT = __hip_bfloat16;
  static __device__ __forceinline__ bool want(const float* fl){ return fl[0] > 0.5f; }
  static __device__ __forceinline__ float ld(const void* p, size_t i){
    return __uint_as_float(((unsigned)((const unsigned short*)p)[i]) << 16);
  }
  static __device__ __forceinline__ void ld8(const void* p, size_t i, float* f){
    uint4 u = *reinterpret_cast<const uint4*>((const unsigned short*)p + i);
    f[0]=__uint_as_float(u.x<<16); f[1]=__uint_as_float(u.x&0xffff0000u);
    f[2]=__uint_as_float(u.y<<16); f[3]=__uint_as_float(u.y&0xffff0000u);
    f[4]=__uint_as_float(u.z<<16); f[5]=__uint_as_float(u.z&0xffff0000u);
    f[6]=__uint_as_float(u.w<<16); f[7]=__uint_as_float(u.w&0xffff0000u);
  }
  static __device__ __forceinline__ void ld4(const void* p, size_t i, float* f){
    uint2 u = *reinterpret_cast<const uint2*>((const unsigned short*)p + i);
    f[0]=__uint_as_float(u.x<<16); f[1]=__uint_as_float(u.x&0xffff0000u);
    f[2]=__uint_as_float(u.y<<16); f[3]=__uint_as_float(u.y&0xffff0000u);
  }
  static __device__ __forceinline__ void st(void* p, size_t i, float v){
    ((__hip_bfloat16*)p)[i] = __float2bfloat16(v);
  }
  static __device__ __forceinline__ void st8(void* p, size_t i, const float* f){
    __hip_bfloat16 h[8];
    #pragma unroll
    for(int j=0;j<8;j++) h[j]=__float2bfloat16(f[j]);
    *reinterpret_cast<uint4*>((__hip_bfloat16*)p + i) = *reinterpret_cast<const uint4*>(h);
  }
};
struct IOf {
  using OT = float;
  static __device__ __forceinline__ bool want(const float* fl){ return fl[0] < 0.5f; }
  static __device__ __forceinline__ float ld(const void* p, size_t i){
    return ((const float*)p)[i];
  }
  static __device__ __forceinline__ void ld8(const void* p, size_t i, float* f){
    const float* q = (const float*)p + i;
    float4 a = *reinterpret_cast<const float4*>(q);
    float4 b = *reinterpret_cast<const float4*>(q+4);
    f[0]=a.x; f[1]=a.y; f[2]=a.z; f[3]=a.w;
    f[4]=b.x; f[5]=b.y; f[6]=b.z; f[7]=b.w;
  }
  static __device__ __forceinline__ void ld4(const void* p, size_t i, float* f){
    float4 a = *reinterpret_cast<const float4*>((const float*)p + i);
    f[0]=a.x; f[1]=a.y; f[2]=a.z; f[3]=a.w;
  }
  static __device__ __forceinline__ void st(void* p, size_t i, float v){
    ((float*)p)[i] = v;
  }
  static __device__ __forceinline__ void st8(void* p, size_t i, const float* f){
    float* q = (float*)p + i;
    *reinterpret_cast<float4*>(q)   = make_float4(f[0],f[1],f[2],f[3]);
    *reinterpret_cast<float4*>(q+4) = make_float4(f[4],f[5],f[6],f[7]);
  }
};

__device__ __forceinline__ float ftanh(float x){
  x = fminf(10.f, fmaxf(-10.f, x));
  float a = __expf(2.f*x);
  return 1.f - 2.f/(a+1.f);
}
__device__ __forceinline__ float fsig(float x){ return 1.f/(1.f+__expf(-x)); }

__device__ __forceinline__ float waveSum(float v){
  #pragma unroll
  for(int o=32;o>0;o>>=1) v += __shfl_down(v,o);
  return v;
}
__device__ __forceinline__ float waveMax(float v){
  #pragma unroll
  for(int o=32;o>0;o>>=1) v = fmaxf(v,__shfl_down(v,o));
  return v;
}

__device__ __forceinline__ void ldf8(const float* p, float* f){
  float4 a = *reinterpret_cast<const float4*>(p);
  float4 b = *reinterpret_cast<const float4*>(p+4);
  f[0]=a.x; f[1]=a.y; f[2]=a.z; f[3]=a.w;
  f[4]=b.x; f[5]=b.y; f[6]=b.z; f[7]=b.w;
}
__device__ __forceinline__ void stf8(float* p, const float* f){
  *reinterpret_cast<float4*>(p)   = make_float4(f[0],f[1],f[2],f[3]);
  *reinterpret_cast<float4*>(p+4) = make_float4(f[4],f[5],f[6],f[7]);
}

// detect input dtype from mask_select (all ones): bf16 pair 1.0,1.0 = 0x3F803F80
__global__ void k_detect(const void* mask, float* flagp){
  if(blockIdx.x==0 && threadIdx.x==0){
    unsigned u = *(const unsigned*)mask;
    flagp[0] = (((u>>16)==0x3F80u) && ((u&0xFFFFu)==0x3F80u)) ? 1.f : 0.f;
  }
}

__global__ void k_zero4(float4* p, int n){
  int i = blockIdx.x*256+threadIdx.x; if(i<n) p[i]=make_float4(0.f,0.f,0.f,0.f);
}

// P0: build A0 = [c_t_1 | emb[y]] as f32  (grid B, block 192, tid<144 active)
template<class IO>
__global__ void k_prep0(const float* flag, const int* y, const void* c_t_1, const void* emb, float* A0){
  if(!IO::want(flag)) return;
  int b = blockIdx.x, tid = threadIdx.x;
  float f[8];
  if(tid < 128){
    IO::ld8(c_t_1, (size_t)b*H2 + tid*8, f);
    stf8(A0 + (size_t)b*1152 + tid*8, f);
  } else if(tid < 144){
    int yb = y[b];
    IO::ld8(emb, (size_t)yb*E + (tid-128)*8, f);
    stf8(A0 + (size_t)b*1152 + H2 + (tid-128)*8, f);
  }
}

// P1: A1 h-columns = f32(h0)  (grid 32, block 256, 8 elems/thread over B*H)
template<class IO>
__global__ void k_prep_h(const float* flag, const void* h0, float* A1){
  if(!IO::want(flag)) return;
  int t = blockIdx.x*256 + threadIdx.x;
  int n = (t*8)&511, b = (t*8)>>9;
  float f[8];
  IO::ld8(h0, (size_t)b*H + n, f);
  stf8(A1 + (size_t)b*640 + E + n, f);
}

// G: generic split-K small GEMM.  C[b][j] (+)= sum_k A[b][k]*W[j][k] (+bias on kz==0)
// tile: 32 j x 64 b, K-chunks of 32 staged in LDS; grid (N/32, 128/64, KS); CH chunks/block.
// W given as up to 2 row-contiguous segments [W0 (K0 cols) | W1 (K1 cols)]; chunks never straddle.
template<class IO>
__global__ __launch_bounds__(256) void k_gemm(const float* flag, const float* A, int lda,
    const void* W0, int K0, const void* W1, int K1,
    const void* bias, float* C, int ldc, int CH){
  if(!IO::want(flag)) return;
  __shared__ float as[32][66];   // [k][b], pad 66: float2 aligned, 2-way banks (free)
  __shared__ float wsm[32][36];  // [k][j], pad 36: float4 aligned, broadcast reads
  int tid = threadIdx.x;
  int j0 = blockIdx.x*32;
  int b0 = blockIdx.y*64;
  int kz = blockIdx.z;
  int bq = tid & 31, jg = tid >> 5;
  float acc[2][4];
  #pragma unroll
  for(int i=0;i<2;i++){
    #pragma unroll
    for(int jj=0;jj<4;jj++) acc[i][jj]=0.f;
  }
  int arow = tid>>2, ac = (tid&3)*8;   // A stage: 64 rows x 32 k, 4 thr/row (128B chunks)

  for(int ci=0; ci<CH; ci++){
    int k0 = (kz*CH + ci)*32;
    __syncthreads();
    { // stage A (f32, coalesced 128B per 4 threads)
      const float* p = A + (size_t)(b0 + arow)*lda + k0 + ac;
      float4 q0 = *reinterpret_cast<const float4*>(p);
      float4 q1 = *reinterpret_cast<const float4*>(p+4);
      as[ac+0][arow]=q0.x; as[ac+1][arow]=q0.y; as[ac+2][arow]=q0.z; as[ac+3][arow]=q0.w;
      as[ac+4][arow]=q1.x; as[ac+5][arow]=q1.y; as[ac+6][arow]=q1.z; as[ac+7][arow]=q1.w;
    }
    if(tid < 128){ // stage W: 32 rows x 32 k, 4 thr/row
      const void* Wp; int st, kr;
      if(k0 < K0){ Wp=W0; st=K0; kr=k0; } else { Wp=W1; st=K1; kr=k0-K0; }
      int wrow = tid>>2, wc = (tid&3)*8;
      float f[8]; IO::ld8(Wp, (size_t)(j0+wrow)*st + kr + wc, f);
      #pragma unroll
      for(int i=0;i<8;i++) wsm[wc+i][wrow] = f[i];
    }
    __syncthreads();
    #pragma unroll
    for(int kk=0; kk<32; kk++){
      float2 a = *reinterpret_cast<const float2*>(&as[kk][bq*2]);
      float4 w = *reinterpret_cast<const float4*>(&wsm[kk][jg*4]);
      acc[0][0] += a.x*w.x; acc[0][1] += a.x*w.y; acc[0][2] += a.x*w.z; acc[0][3] += a.x*w.w;
      acc[1][0] += a.y*w.x; acc[1][1] += a.y*w.y; acc[1][2] += a.y*w.z; acc[1][3] += a.y*w.w;
    }
  }
  if(kz==0 && bias){
    #pragma unroll
    for(int jj=0;jj<4;jj++){
      float bv = IO::ld(bias, j0 + jg*4 + jj);
      acc[0][jj] += bv; acc[1][jj] += bv;
    }
  }
  #pragma unroll
  for(int i=0;i<2;i++){
    float* cp = C + (size_t)(b0 + bq*2 + i)*ldc + j0 + jg*4;
    atomicAdd(cp+0, acc[i][0]); atomicAdd(cp+1, acc[i][1]);
    atomicAdd(cp+2, acc[i][2]); atomicAdd(cp+3, acc[i][3]);
  }
}

// CELL: LSTM elementwise (grid 32, block 256, 8 elems/thread over B*H)
template<class IO>
__global__ void k_cell(const float* flag, const float* gts, const void* c0,
                       const void* b_ih, const void* b_hh,
                       float* A2, float* A3, void* dout){
  if(!IO::want(flag)) return;
  int t = blockIdx.x*256 + threadIdx.x;
  int n = (t*8)&511, b = (t*8)>>9;
  size_t gb = (size_t)b*H4 + n;
  float gi[8],gf[8],gg[8],go[8],c0v[8];
  ldf8(gts+gb,        gi); ldf8(gts+gb+H,   gf);
  ldf8(gts+gb+2*H,    gg); ldf8(gts+gb+3*H, go);
  float bi0[8],bi1[8],bi2[8],bi3[8],bh0[8],bh1[8],bh2[8],bh3[8];
  IO::ld8(b_ih, n, bi0); IO::ld8(b_ih, H+n, bi1); IO::ld8(b_ih, 2*H+n, bi2); IO::ld8(b_ih, 3*H+n, bi3);
  IO::ld8(b_hh, n, bh0); IO::ld8(b_hh, H+n, bh1); IO::ld8(b_hh, 2*H+n, bh2); IO::ld8(b_hh, 3*H+n, bh3);
  IO::ld8(c0, (size_t)b*H + n, c0v);
  float hv[8], cv[8];
  #pragma unroll
  for(int j=0;j<8;j++){
    float ig = fsig (gi[j]+bi0[j]+bh0[j]);
    float fg = fsig (gf[j]+bi1[j]+bh1[j]);
    float gv = ftanh(gg[j]+bi2[j]+bh2[j]);
    float og = fsig (go[j]+bi3[j]+bh3[j]);
    float c = fg*c0v[j] + ig*gv;
    cv[j]=c; hv[j]=og*ftanh(c);
  }
  stf8(A2 + (size_t)b*H2 + n,     hv);
  stf8(A2 + (size_t)b*H2 + H + n, cv);
  stf8(A3 + (size_t)b*1536 + n,   hv);
  IO::st8(dout, (size_t)OFF_H + (size_t)b*H + n, hv);
  IO::st8(dout, (size_t)OFF_C + (size_t)b*H + n, cv);
}

// K4: attention scores  (grid B*25, block 256 = 4 waves, 16 t per block)
template<class IO>
__global__ void k_scores(const float* flag, const void* enc_feat, const float* ws_dec,
                         const void* W_c, const void* v_w, const void* coverage,
                         float* ws_scores){
  if(!IO::want(flag)) return;
  int blk = blockIdx.x;
  int b  = blk / (T/16);
  int tb = (blk % (T/16))*16;
  int tid = threadIdx.x;
  int wave = tid >> 6, lane = tid & 63;
  int n0 = lane*16;
  float dec[16], wc[16], vw[16];
  #pragma unroll
  for(int i=0;i<16;i+=4){
    float4 v4 = *reinterpret_cast<const float4*>(ws_dec + b*H2 + n0 + i);
    dec[i]=v4.x; dec[i+1]=v4.y; dec[i+2]=v4.z; dec[i+3]=v4.w;
  }
  IO::ld8(W_c, n0, wc); IO::ld8(W_c, n0+8, wc+8);
  IO::ld8(v_w, n0, vw); IO::ld8(v_w, n0+8, vw+8);
  #pragma unroll
  for(int it=0; it<4; ++it){
    int t = tb + wave*4 + it;
    float cov = IO::ld(coverage, (size_t)b*T + t);
    size_t base = ((size_t)b*T + t)*H2 + n0;
    float ef[16]; IO::ld8(enc_feat, base, ef); IO::ld8(enc_feat, base+8, ef+8);
    float sum=0.f;
    #pragma unroll
    for(int i=0;i<16;i++){
      float s = ef[i] + dec[i] + cov*wc[i];
      sum += ftanh(s)*vw[i];
    }
    sum = waveSum(sum);
    if(lane==0) ws_scores[b*T + t] = sum;
  }
}

// K5: softmax over T + mask + renorm + coverage_next  (grid B, block 512)
template<class IO>
__global__ void k_attn(const float* flag, const float* ws_scores, const void* mask,
                       const void* coverage, float* ws_attn, void* dout){
  if(!IO::want(flag)) return;
  __shared__ float red[8];
  __shared__ float bc0, bc1, bc2;
  int b=blockIdx.x, tid=threadIdx.x;
  int lane = tid & 63, w = tid >> 6;
  float s = (tid<T)? ws_scores[b*T+tid] : -3.0e38f;
  float m = waveMax(s);
  if(lane==0) red[w]=m;
  __syncthreads();
  if(tid==0){ float v=red[0]; for(int i=1;i<8;i++)v=fmaxf(v,red[i]); bc0=v; }
  __syncthreads();
  float e = (tid<T)? __expf(s-bc0) : 0.f;
  float sm = waveSum(e);
  if(lane==0) red[w]=sm;
  __syncthreads();
  if(tid==0){ float v=0; for(int i=0;i<8;i++)v+=red[i]; bc1=v; }
  __syncthreads();
  float attn_ = (tid<T)? (e/bc1)*IO::ld(mask, (size_t)b*T+tid) : 0.f;
  float s2 = waveSum(attn_);
  if(lane==0) red[w]=s2;
  __syncthreads();
  if(tid==0){ float v=0; for(int i=0;i<8;i++)v+=red[i]; bc2=v; }
  __syncthreads();
  float attn = attn_/(bc2+EPSF);
  if(tid<T){
    ws_attn[b*T+tid]=attn;
    IO::st(dout, (size_t)OFF_AT + b*T+tid, attn);
    IO::st(dout, (size_t)OFF_COV + b*T+tid, IO::ld(coverage,(size_t)b*T+tid)+attn);
  }
}

// K6: c_t = attn @ encoder_outputs into A3 ct-columns  (grid B*8, block 256)
template<class IO>
__global__ void k_ctx(const float* flag, const void* enc_out, const float* ws_attn, float* A3){
  if(!IO::want(flag)) return;
  __shared__ float at[50];
  int b = blockIdx.x>>3, ch = blockIdx.x&7, tid=threadIdx.x;
  if(tid<50) at[tid] = ws_attn[b*T + ch*50 + tid];
  __syncthreads();
  int n0 = tid*4;
  float a0=0,a1=0,a2=0,a3=0;
  size_t base = ((size_t)b*T + ch*50)*H2 + n0;
  for(int t=0;t<50;t++){
    float a = at[t];
    float f[4]; IO::ld4(enc_out, base, f);
    a0 += a*f[0]; a1 += a*f[1]; a2 += a*f[2]; a3 += a*f[3];
    base += H2;
  }
  float* cp = A3 + (size_t)b*1536 + H + n0;
  atomicAdd(cp+0, a0); atomicAdd(cp+1, a1);
  atomicAdd(cp+2, a2); atomicAdd(cp+3, a3);
}

// K7: p_gen + write c_t out  (grid B, block 256)
template<class IO>
__global__ void k_pgen(const float* flag, const float* A1, const float* A2, const float* A3,
                       const void* W_pg, const void* b_pg, float* ws_pg, void* dout){
  if(!IO::want(flag)) return;
  __shared__ float red[4];
  int b=blockIdx.x, tid=threadIdx.x;
  int lane = tid&63, w = tid>>6;
  float part=0.f;
  for(int k=tid;k<KPG;k+=256){
    float xv;
    if(k<H2)            xv = A3[(size_t)b*1536 + H + k];          // c_t
    else if(k<H2+H)     xv = A2[(size_t)b*H2 + (k-H2)];           // h
    else if(k<2*H2)     xv = A2[(size_t)b*H2 + H + (k-H2-H)];     // c
    else                xv = A1[(size_t)b*640 + (k-2*H2)];        // x
    part += xv * IO::ld(W_pg, k);
  }
  part = waveSum(part);
  if(lane==0) red[w]=part;
  __syncthreads();
  if(tid==0){
    float v = red[0]+red[1]+red[2]+red[3] + IO::ld(b_pg, 0);
    float pg = fsig(v);
    ws_pg[b]=pg;
    IO::st(dout, (size_t)OFF_PG + b, pg);
  }
  for(int k=tid;k<H2;k+=256) IO::st(dout, (size_t)OFF_CT + b*H2+k, A3[(size_t)b*1536 + H + k]);
}

// K9: logits = o1 @ W_o2^T + b_o2   (grid ceil(V/64), block 256; tile 128b x 64v, K-chunk 32)
template<class IO>
__global__ __launch_bounds__(256) void k_logits(const float* flag, const float* ws_o1,
                                                const void* W_o2, const void* b_o2,
                                                float* ws_logits){
  if(!IO::want(flag)) return;
  __shared__ float o1s[32][132];
  __shared__ float wvs[32][68];
  int v0 = blockIdx.x * 64;
  int tid = threadIdx.x;
  int bg = tid & 31;   // b = bg*4 + i
  int vg = tid >> 5;   // v = v0 + vg*8 + j
  float acc[4][8];
  #pragma unroll
  for(int i=0;i<4;i++){
    #pragma unroll
    for(int j=0;j<8;j++) acc[i][j]=0.f; }
  for(int k0=0;k0<H;k0+=32){
    __syncthreads();
    { // stage o1: 128 rows x 32 k, 16 floats per thread
      int bb = tid>>1, kc = (tid&1)*16;
      const float* q = ws_o1 + bb*H + k0 + kc;
      float4 q0 = *reinterpret_cast<const float4*>(q);
      float4 q1 = *reinterpret_cast<const float4*>(q+4);
      float4 q2 = *reinterpret_cast<const float4*>(q+8);
      float4 q3 = *reinterpret_cast<const float4*>(q+12);
      o1s[kc+ 0][bb]=q0.x; o1s[kc+ 1][bb]=q0.y; o1s[kc+ 2][bb]=q0.z; o1s[kc+ 3][bb]=q0.w;
      o1s[kc+ 4][bb]=q1.x; o1s[kc+ 5][bb]=q1.y; o1s[kc+ 6][bb]=q1.z; o1s[kc+ 7][bb]=q1.w;
      o1s[kc+ 8][bb]=q2.x; o1s[kc+ 9][bb]=q2.y; o1s[kc+10][bb]=q2.z; o1s[kc+11][bb]=q2.w;
      o1s[kc+12][bb]=q3.x; o1s[kc+13][bb]=q3.y; o1s[kc+14][bb]=q3.z; o1s[kc+15][bb]=q3.w;
    }
    { // stage W_o2: 64 v x 32 k, 8 per thread
      int vv = tid>>2, c = (tid&3)*8;
      int v = v0+vv; bool ok = (v<V);
      float f[8]; IO::ld8(W_o2, (size_t)(ok? v : (V-1))*H + k0 + c, f);
      #pragma unroll
      for(int j=0;j<8;j++) wvs[c+j][vv] = ok? f[j] : 0.f;
    }
    __syncthreads();
    #pragma unroll 8
    for(int kk=0;kk<32;kk++){
      float4 a  = *reinterpret_cast<const float4*>(&o1s[kk][bg*4]);
      float4 w0 = *reinterpret_cast<const float4*>(&wvs[kk][vg*8]);
      float4 w1 = *reinterpret_cast<const float4*>(&wvs[kk][vg*8+4]);
      float av[4]={a.x,a.y,a.z,a.w};
      float wv[8]={w0.x,w0.y,w0.z,w0.w,w1.x,w1.y,w1.z,w1.w};
      #pragma unroll
      for(int i=0;i<4;i++){
        #pragma unroll
        for(int j=0;j<8;j++) acc[i][j] += av[i]*wv[j];
      }
    }
  }
  #pragma unroll
  for(int i=0;i<4;i++){
    int bb = bg*4+i;
    #pragma unroll
    for(int j=0;j<8;j++){
      int v = v0 + vg*8 + j;
      if(v<V) ws_logits[(size_t)bb*V + v] = acc[i][j] + IO::ld(b_o2, v);
    }
  }
}

// K10a-1: partial softmax reduce per 2000-elem chunk  (grid B*25, block 256)
__global__ void k_vred(const float* lg, float* pm){
  __shared__ float red[4];
  __shared__ float bcm;
  int b = blockIdx.x / VCH, ch = blockIdx.x % VCH;
  int tid = threadIdx.x;
  int lane = tid&63, w = tid>>6;
  bool act = tid < (VCHUNK/8);
  float f[8];
  float m = -3.0e38f;
  if(act){
    ldf8(lg + (size_t)b*V + ch*VCHUNK + tid*8, f);
    #pragma unroll
    for(int j=0;j<8;j++) m = fmaxf(m, f[j]);
  }
  m = waveMax(m);
  if(lane==0) red[w]=m;
  __syncthreads();
  if(tid==0) bcm = fmaxf(fmaxf(red[0],red[1]),fmaxf(red[2],red[3]));
  __syncthreads();
  float mx = bcm;
  float s = 0.f;
  if(act){
    #pragma unroll
    for(int j=0;j<8;j++) s += __expf(f[j]-mx);
  }
  s = waveSum(s);
  if(lane==0) red[w]=s;
  __syncthreads();
  if(tid==0){
    float sv = red[0]+red[1]+red[2]+red[3];
    pm[(b*VCH+ch)*2+0] = mx;
    pm[(b*VCH+ch)*2+1] = sv;
  }
}

// K10a-2: combine 25 partials per row + fold p_gen  (grid B, block 64)
__global__ void k_vcomb(const float* pm, const float* pg, float* mxsc){
  int b = blockIdx.x, tid = threadIdx.x;
  float m = (tid<VCH)? pm[(b*VCH+tid)*2+0] : -3.0e38f;
  float M = waveMax(m);
  M = __shfl(M, 0);
  float s = (tid<VCH)? pm[(b*VCH+tid)*2+1]*__expf(m-M) : 0.f;
  s = waveSum(s);
  if(tid==0){
    mxsc[b*2+0] = M;
    mxsc[b*2+1] = pg[b]/s;
  }
}

// K10a-3: fin = exp(lg-mx)*scale, 8/thread  (grid B*V/8/256 = 3125, block 256)
__global__ void k_vscale(const float* lg, const float* mxsc, float* fin){
  int i = blockIdx.x*256 + threadIdx.x;
  if(i >= B*(V/8)) return;
  int b = i / (V/8);
  size_t off = (size_t)b*V + (size_t)(i - b*(V/8))*8;
  float mx = mxsc[b*2+0], sc = mxsc[b*2+1];
  float f[8]; ldf8(lg+off, f);
  #pragma unroll
  for(int j=0;j<8;j++) f[j] = __expf(f[j]-mx)*sc;
  stf8(fin+off, f);
}

// K10b: scatter-add (1-p_gen)*attn  (grid ceil(B*T/256))
__global__ void k_scatter(const int* ext, const float* ws_attn, const float* ws_pg, float* ws_final){
  int i = blockIdx.x*256+threadIdx.x;
  if(i>=B*T) return;
  int b=i/T;
  float add = (1.f-ws_pg[b])*ws_attn[i];
  atomicAdd(&ws_final[(size_t)b*V + ext[i]], add);
}

// K10c: store final dist to out, 8/thread
template<class IO>
__global__ void k_tostore(const float* flag, const float* src, void* dout, int n8){
  if(!IO::want(flag)) return;
  int i = blockIdx.x*256+threadIdx.x;
  if(i>=n8) return;
  size_t off = (size_t)i*8;
  float f[8];
  ldf8(src + off, f);
  IO::st8(dout, (size_t)OFF_FIN + off, f);
}

extern "C" void kernel_launch(void* const* d_in, const int* in_sizes, int n_in,
                              void* d_out, int out_size, void* d_ws, size_t ws_size,
                              hipStream_t stream){
  const int* y_t_1 = (const int*)d_in[0];
  const void* h0   =d_in[1];  const void* c0   =d_in[2];  const void* c_t_1=d_in[3];
  const void* enc_out=d_in[4]; const void* enc_feat=d_in[5]; const void* mask=d_in[6];
  const int* ext = (const int*)d_in[7];
  const void* coverage=d_in[8]; const void* emb=d_in[9];  const void* W_c=d_in[10];
  const void* W_dp=d_in[11];   const void* b_dp=d_in[12]; const void* v_w=d_in[13];
  const void* W_xc=d_in[14];   const void* b_xc=d_in[15];
  const void* W_ih=d_in[16];   const void* W_hh=d_in[17];
  const void* b_ih=d_in[18];   const void* b_hh=d_in[19];
  const void* W_pg=d_in[20];   const void* b_pg=d_in[21];
  const void* W_o1=d_in[22];   const void* b_o1=d_in[23];
  const void* W_o2=d_in[24];   const void* b_o2=d_in[25];

  float* ws = (float*)d_ws;
  // zero-initialized accumulation block (475136 f32 = 118784 float4):
  float* ws_A1  = ws;                        // [x(128) | h0(512)]  128*640
  float* ws_dec = ws_A1  + 128*640;          // 128*1024
  float* ws_o1  = ws_dec + 128*1024;         // 128*512
  float* ws_A3  = ws_o1  + 128*512;          // [h(512) | c_t(1024)] 128*1536
  // non-zeroed:
  float* ws_A2  = ws_A3  + 128*1536;         // [h(512) | c(512)]   128*1024
  float* ws_sc  = ws_A2  + 128*1024;         // B*T (scores; dead after k_attn -> reused for softmax partials)
  float* ws_attn= ws_sc  + B*T;              // B*T
  float* ws_pg  = ws_attn+ B*T;              // B
  float* ws_log = ws_pg  + B;                // B*V
  float* ws_gates = ws_log;                  // alias: 128*2048 (consumed before k_logits)
  float* ws_A0    = ws_log + 128*2048;       // alias: [c_t_1|emb] 128*1152
  float* ws_flag  = ws_log + (size_t)B*V;    // 4
  float* ws_pm    = ws_sc;                   // alias: B*25*2 partial (m,s)
  float* ws_mxsc  = ws_sc + 2*B*VCH;         // alias: B*2 (mx, scale)

  k_detect<<<dim3(1), dim3(64), 0, stream>>>(mask, ws_flag);
  k_zero4 <<<dim3(464), dim3(256), 0, stream>>>((float4*)ws, 118784);
  k_zero4 <<<dim3(256), dim3(256), 0, stream>>>((float4*)ws_gates, 65536);

  k_prep0<IOb><<<dim3(B), dim3(192), 0, stream>>>(ws_flag, y_t_1, c_t_1, emb, ws_A0);
  k_prep0<IOf><<<dim3(B), dim3(192), 0, stream>>>(ws_flag, y_t_1, c_t_1, emb, ws_A0);
  k_prep_h<IOb><<<dim3(32), dim3(256), 0, stream>>>(ws_flag, h0, ws_A1);
  k_prep_h<IOf><<<dim3(32), dim3(256), 0, stream>>>(ws_flag, h0, ws_A1);

  // embed: x = A0 @ W_xc^T + b_xc -> A1 x-columns.  N=128,K=1152, KS=12, CH=3
  k_gemm<IOb><<<dim3(4,2,12), dim3(256), 0, stream>>>(ws_flag, ws_A0, 1152, W_xc, 1152, nullptr, 0, b_xc, ws_A1, 640, 3);
  k_gemm<IOf><<<dim3(4,2,12), dim3(256), 0, stream>>>(ws_flag, ws_A0, 1152, W_xc, 1152, nullptr, 0, b_xc, ws_A1, 640, 3);

  // gates: A1 @ [W_ih|W_hh]^T -> ws_gates.  N=2048,K=640, KS=2, CH=10 (biases in k_cell)
  k_gemm<IOb><<<dim3(64,2,2), dim3(256), 0, stream>>>(ws_flag, ws_A1, 640, W_ih, E, W_hh, H, nullptr, ws_gates, H4, 10);
  k_gemm<IOf><<<dim3(64,2,2), dim3(256), 0, stream>>>(ws_flag, ws_A1, 640, W_ih, E, W_hh, H, nullptr, ws_gates, H4, 10);

  k_cell<IOb><<<dim3(32), dim3(256), 0, stream>>>(ws_flag, ws_gates, c0, b_ih, b_hh, ws_A2, ws_A3, d_out);
  k_cell<IOf><<<dim3(32), dim3(256), 0, stream>>>(ws_flag, ws_gates, c0, b_ih, b_hh, ws_A2, ws_A3, d_out);

  // dec_fea: A2 @ W_dp^T + b_dp -> ws_dec.  N=1024,K=1024, KS=4, CH=8
  k_gemm<IOb><<<dim3(32,2,4), dim3(256), 0, stream>>>(ws_flag, ws_A2, H2, W_dp, H2, nullptr, 0, b_dp, ws_dec, H2, 8);
  k_gemm<IOf><<<dim3(32,2,4), dim3(256), 0, stream>>>(ws_flag, ws_A2, H2, W_dp, H2, nullptr, 0, b_dp, ws_dec, H2, 8);

  k_scores<IOb><<<dim3(B*(T/16)), dim3(256), 0, stream>>>(ws_flag, enc_feat, ws_dec, W_c, v_w, coverage, ws_sc);
  k_scores<IOf><<<dim3(B*(T/16)), dim3(256), 0, stream>>>(ws_flag, enc_feat, ws_dec, W_c, v_w, coverage, ws_sc);

  k_attn<IOb><<<dim3(B), dim3(512), 0, stream>>>(ws_flag, ws_sc, mask, coverage, ws_attn, d_out);
  k_attn<IOf><<<dim3(B), dim3(512), 0, stream>>>(ws_flag, ws_sc, mask, coverage, ws_attn, d_out);

  k_ctx<IOb><<<dim3(B*8), dim3(256), 0, stream>>>(ws_flag, enc_out, ws_attn, ws_A3);
  k_ctx<IOf><<<dim3(B*8), dim3(256), 0, stream>>>(ws_flag, enc_out, ws_attn, ws_A3);

  k_pgen<IOb><<<dim3(B), dim3(256), 0, stream>>>(ws_flag, ws_A1, ws_A2, ws_A3, W_pg, b_pg, ws_pg, d_out);
  k_pgen<IOf><<<dim3(B), dim3(256), 0, stream>>>(ws_flag, ws_A1, ws_A2, ws_A3, W_pg, b_pg, ws_pg, d_out);

  // o1: A3 @ W_o1^T + b_o1 -> ws_o1.  N=512,K=1536, KS=8, CH=6
  k_gemm<IOb><<<dim3(16,2,8), dim3(256), 0, stream>>>(ws_flag, ws_A3, 1536, W_o1, 1536, nullptr, 0, b_o1, ws_o1, H, 6);
  k_gemm<IOf><<<dim3(16,2,8), dim3(256), 0, stream>>>(ws_flag, ws_A3, 1536, W_o1, 1536, nullptr, 0, b_o1, ws_o1, H, 6);

  k_logits<IOb><<<dim3((V+63)/64), dim3(256), 0, stream>>>(ws_flag, ws_o1, W_o2, b_o2, ws_log);
  k_logits<IOf><<<dim3((V+63)/64), dim3(256), 0, stream>>>(ws_flag, ws_o1, W_o2, b_o2, ws_log);

  // vocab softmax: split reduce -> combine -> scale (all f32 workspace, single launch each)
  k_vred  <<<dim3(B*VCH), dim3(256), 0, stream>>>(ws_log, ws_pm);
  k_vcomb <<<dim3(B), dim3(64), 0, stream>>>(ws_pm, ws_pg, ws_mxsc);
  k_vscale<<<dim3(B*(V/8)/256), dim3(256), 0, stream>>>(ws_log, ws_mxsc, ws_log);

  k_scatter <<<dim3((B*T+255)/256), dim3(256), 0, stream>>>(ext, ws_attn, ws_pg, ws_log);

  k_tostore<IOb><<<dim3((B*V/8+255)/256), dim3(256), 0, stream>>>(ws_flag, ws_log, d_out, B*V/8);
  k_tostore<IOf><<<dim3((B*V/8+255)/256), dim3(256), 0, stream>>>(ws_flag, ws_log, d_out, B*V/8);
}